// Round 1
// baseline (901.539 us; speedup 1.0000x reference)
//
#include <hip/hip_runtime.h>

// HungarianMatcher on MI355X.
// Output 0: C (16, 1024, 1536) fp32 cost matrix.
// Output 1: matched_query (16, 96) written as fp32 values.

#define BSZ   16
#define NQ    1024
#define NTGT  96
#define NCLS  4
#define DD    6
#define NCOLS (BSZ * NTGT)   // 1536
#define NROWS (BSZ * NQ)     // 16384
#define HINF  1e9f

// ---------------------------------------------------------------------------
// Kernel 1: cost matrix. One block per (b, q) row, 384 threads x 4 cols each.
// Also scatters the batch-diagonal 96x1024 block (transposed) into ws for
// coalesced row reads in the Hungarian kernel.
// ---------------------------------------------------------------------------
__global__ __launch_bounds__(384) void cost_kernel(
    const float* __restrict__ logits,   // (16384, 4)
    const float* __restrict__ boxes,    // (16384, 6)
    const int*   __restrict__ labels,   // (1536)
    const float* __restrict__ tgt,      // (1536, 6)
    float* __restrict__ C,              // (16384, 1536)
    float* __restrict__ tws,            // (1536, 1024) transposed blocks
    int use_ws)
{
    const int row = blockIdx.x;          // 0..16383  (b*1024 + q)
    const int b   = row >> 10;
    const int q   = row & (NQ - 1);
    const int tid = threadIdx.x;

    // Uniform per-row data (blockIdx-based -> scalar loads).
    const float4 lg = *reinterpret_cast<const float4*>(logits + (size_t)row * NCLS);
    const float mx = fmaxf(fmaxf(lg.x, lg.y), fmaxf(lg.z, lg.w));
    const float e0 = expf(lg.x - mx), e1 = expf(lg.y - mx);
    const float e2 = expf(lg.z - mx), e3 = expf(lg.w - mx);
    const float s  = (e0 + e1) + (e2 + e3);
    const float p0 = e0 / s, p1 = e1 / s, p2 = e2 / s, p3 = e3 / s;

    float bx[DD];
#pragma unroll
    for (int d = 0; d < DD; ++d) bx[d] = boxes[(size_t)row * DD + d];

    const int colbase = tid * 4;
    const int4 lb = *reinterpret_cast<const int4*>(labels + colbase);
    const int cls[4] = {lb.x, lb.y, lb.z, lb.w};

    // 4 targets x 6 dims = 24 consecutive floats = 6 x float4 (96B, 16B aligned).
    float tv[24];
    const float4* tg = reinterpret_cast<const float4*>(tgt + (size_t)colbase * DD);
#pragma unroll
    for (int d = 0; d < 6; ++d) {
        const float4 t4 = tg[d];
        tv[d * 4 + 0] = t4.x; tv[d * 4 + 1] = t4.y;
        tv[d * 4 + 2] = t4.z; tv[d * 4 + 3] = t4.w;
    }

    float out[4];
#pragma unroll
    for (int c = 0; c < 4; ++c) {
        float cb = 0.f;
#pragma unroll
        for (int d = 0; d < DD; ++d) cb += fabsf(bx[d] - tv[c * DD + d]);
        const int cl = cls[c];
        const float pc = (cl & 2) ? ((cl & 1) ? p3 : p2) : ((cl & 1) ? p1 : p0);
        out[c] = cb - pc;   // COST_BBOX*cdist + COST_CLASS*(-prob)
    }

    *reinterpret_cast<float4*>(C + (size_t)row * NCOLS + colbase) =
        make_float4(out[0], out[1], out[2], out[3]);

    if (use_ws) {
#pragma unroll
        for (int c = 0; c < 4; ++c) {
            const int col = colbase + c;
            const int t = col - b * NTGT;
            if (t >= 0 && t < NTGT)
                tws[(size_t)col * NQ + q] = out[c];   // tws[(b*96+t)*1024 + q]
        }
    }
}

// ---------------------------------------------------------------------------
// Kernel 2: Jonker-Volgenant Hungarian, one 64-lane wave per batch.
// Exact replica of the reference arithmetic (fp32, INF=1e9, first-min
// tie-break) so the assignment matches bit-for-bit.
// Columns j in [0,1024]; lane owns j = k*64 + lane for k in [0,17).
// v, minv in registers; used as a 17-bit mask; p/way/u in LDS.
// ---------------------------------------------------------------------------
__global__ __launch_bounds__(64) void hungarian_kernel(
    const float* __restrict__ C,       // (16384, 1536)
    const float* __restrict__ tws,     // (1536, 1024)
    int use_ws,
    float* __restrict__ out_match)     // (16*96) as floats
{
    const int b    = blockIdx.x;
    const int lane = threadIdx.x;

    __shared__ int   p[NQ + 1];     // col -> matched row (0 = free)
    __shared__ int   way[NQ + 1];
    __shared__ float u[NTGT + 1];

    for (int j = lane; j < NQ + 1; j += 64) { p[j] = 0; way[j] = 0; }
    for (int r = lane; r < NTGT + 1; r += 64) u[r] = 0.f;

    float v[17];
#pragma unroll
    for (int k = 0; k < 17; ++k) v[k] = 0.f;
    __syncthreads();

    // a[i0][j] = cost[i0-1][j-1] = C[b][j-1][b*96 + (i0-1)]
    const float* Cb = C + (size_t)b * NQ * NCOLS + b * NTGT;  // Cb[q*1536 + t]
    const float* Tb = tws + (size_t)b * NTGT * NQ;            // Tb[t*1024 + q]

    for (int i = 1; i <= NTGT; ++i) {
        if (lane == 0) p[0] = i;
        float minv[17];
#pragma unroll
        for (int k = 0; k < 17; ++k) minv[k] = HINF;
        unsigned usedmask = 0;
        int j0 = 0;
        __syncthreads();

        // ---- Dijkstra phase ----
        for (;;) {
            const int i0 = p[j0];              // broadcast LDS read
            if (i0 == 0) break;                // j0 is a free column
            if ((j0 & 63) == lane) usedmask |= (1u << (j0 >> 6));
            const float u_i0 = u[i0];
            const int t = i0 - 1;
            const float* rT = Tb + (size_t)t * NQ;
            const float* rC = Cb + t;

            float bestv = HINF;
            int   bestj = 0x7fffffff;
#pragma unroll
            for (int k = 0; k < 17; ++k) {
                const int j = k * 64 + lane;
                const bool inb = (j >= 1) && (j <= NQ);
                const bool un  = inb && !((usedmask >> k) & 1u);
                if (un) {
                    const float a = use_ws ? rT[j - 1]
                                           : rC[(size_t)(j - 1) * NCOLS];
                    const float cur = a - u_i0 - v[k];
                    if (cur < minv[k]) { minv[k] = cur; way[j] = j0; }
                    const float m = minv[k];
                    if (m < bestv || (m == bestv && j < bestj)) {
                        bestv = m; bestj = j;
                    }
                }
            }
            // wave argmin, first-index tie-break (matches jnp.argmin)
#pragma unroll
            for (int off = 32; off > 0; off >>= 1) {
                const float ov = __shfl_down(bestv, off, 64);
                const int   oj = __shfl_down(bestj, off, 64);
                if (ov < bestv || (ov == bestv && oj < bestj)) {
                    bestv = ov; bestj = oj;
                }
            }
            const float delta = __shfl(bestv, 0, 64);
            const int   j1    = __shfl(bestj, 0, 64);

            // updates: used j -> u[p[j]] += delta, v[j] -= delta;
            //          unused j -> minv[j] -= delta
#pragma unroll
            for (int k = 0; k < 17; ++k) {
                const int j = k * 64 + lane;
                if (j <= NQ) {
                    if ((usedmask >> k) & 1u) {
                        const int pj = p[j];      // distinct rows across lanes
                        u[pj] += delta;
                        v[k] -= delta;
                    } else if (j >= 1) {
                        minv[k] -= delta;
                    }
                }
            }
            j0 = j1;
            __syncthreads();   // single wave: cheap; forces LDS ordering
        }

        // ---- augmenting path (uniform across lanes) ----
        while (j0 != 0) {
            const int jn = way[j0];     // broadcast
            const int pv = p[jn];       // broadcast
            if (lane == 0) p[j0] = pv;
            j0 = jn;
        }
        __syncthreads();
    }

    // invert: matched col (query) for each row (target)
#pragma unroll
    for (int k = 0; k < 17; ++k) {
        const int j = k * 64 + lane;
        if (j >= 1 && j <= NQ) {
            const int r = p[j];
            if (r > 0) out_match[b * NTGT + (r - 1)] = (float)(j - 1);
        }
    }
}

extern "C" void kernel_launch(void* const* d_in, const int* in_sizes, int n_in,
                              void* d_out, int out_size, void* d_ws, size_t ws_size,
                              hipStream_t stream) {
    const float* logits = (const float*)d_in[0];   // (16,1024,4)
    const float* boxes  = (const float*)d_in[1];   // (16,1024,6)
    const int*   labels = (const int*)d_in[2];     // (16,96)
    const float* tgt    = (const float*)d_in[3];   // (16,96,6)

    float* C = (float*)d_out;
    float* out_match = C + (size_t)NROWS * NCOLS;  // after 25,165,824 floats

    const size_t need = (size_t)NCOLS * NQ * sizeof(float);   // 6.3 MB
    const int use_ws = (d_ws != nullptr && ws_size >= need) ? 1 : 0;
    float* tws = (float*)d_ws;

    cost_kernel<<<NROWS, 384, 0, stream>>>(logits, boxes, labels, tgt, C, tws, use_ws);
    hungarian_kernel<<<BSZ, 64, 0, stream>>>(C, tws, use_ws, out_match);
}

// Round 2
// 287.815 us; speedup vs baseline: 3.1324x; 3.1324x over previous
//
#include <hip/hip_runtime.h>

// HungarianMatcher on MI355X (gfx950).
// Output 0: C (16, 1024, 1536) fp32 cost matrix.
// Output 1: matched_query (16, 96) written as fp32 values.
//
// R2 design: shifted-potential JV (deferred u/v/minv updates), register-resident
// per-lane column state, DPP min-reduction, no barriers in the Dijkstra loop,
// and the C-matrix build fused into the same kernel so it runs concurrently on
// the other ~240 CUs while 16 single-wave blocks run the matchers.

#define BSZ   16
#define NQ    1024
#define NTGT  96
#define NCLS  4
#define DD    6
#define NCOLS (BSZ * NTGT)   // 1536
#define NROWS (BSZ * NQ)     // 16384
#define LHINF 1e9f
#define NHB   16             // hungarian blocks (one per batch)

// ---------------------------------------------------------------------------
// DPP wave-64 fmin reduction; result valid in lane 63.
// row_shr:1/2/4/8 then row_bcast:15, row_bcast:31. Invalid lanes keep +INF.
// ---------------------------------------------------------------------------
__device__ __forceinline__ float wave_fmin63(float x) {
    const int INF_I = __float_as_int(LHINF);
    int m;
    m = __builtin_amdgcn_update_dpp(INF_I, __float_as_int(x), 0x111, 0xf, 0xf, false);
    x = fminf(x, __int_as_float(m));
    m = __builtin_amdgcn_update_dpp(INF_I, __float_as_int(x), 0x112, 0xf, 0xf, false);
    x = fminf(x, __int_as_float(m));
    m = __builtin_amdgcn_update_dpp(INF_I, __float_as_int(x), 0x114, 0xf, 0xf, false);
    x = fminf(x, __int_as_float(m));
    m = __builtin_amdgcn_update_dpp(INF_I, __float_as_int(x), 0x118, 0xf, 0xf, false);
    x = fminf(x, __int_as_float(m));
    m = __builtin_amdgcn_update_dpp(INF_I, __float_as_int(x), 0x142, 0xf, 0xf, false);
    x = fminf(x, __int_as_float(m));
    m = __builtin_amdgcn_update_dpp(INF_I, __float_as_int(x), 0x143, 0xf, 0xf, false);
    x = fminf(x, __int_as_float(m));
    return x;
}

// Identical op order everywhere so tws and C agree bit-for-bit.
__device__ __forceinline__ float cost_elem6(const float* bx, const float* tv, float psel) {
    float cd = fabsf(bx[0] - tv[0]);
    cd += fabsf(bx[1] - tv[1]);
    cd += fabsf(bx[2] - tv[2]);
    cd += fabsf(bx[3] - tv[3]);
    cd += fabsf(bx[4] - tv[4]);
    cd += fabsf(bx[5] - tv[5]);
    return cd - psel;
}

// ---------------------------------------------------------------------------
// Kernel P: softmax probs per (b,q) row. probs[row][0..3].
// ---------------------------------------------------------------------------
__global__ __launch_bounds__(256) void probs_kernel(
    const float* __restrict__ logits, float* __restrict__ probs)
{
    const int row = blockIdx.x * 256 + threadIdx.x;
    const float4 lg = ((const float4*)logits)[row];
    const float mx = fmaxf(fmaxf(lg.x, lg.y), fmaxf(lg.z, lg.w));
    const float e0 = expf(lg.x - mx), e1 = expf(lg.y - mx);
    const float e2 = expf(lg.z - mx), e3 = expf(lg.w - mx);
    const float s = (e0 + e1) + (e2 + e3);
    ((float4*)probs)[row] = make_float4(e0 / s, e1 / s, e2 / s, e3 / s);
}

// ---------------------------------------------------------------------------
// Kernel A: transposed diagonal blocks. tws[(b*96+t)*1024 + q] = cost(b,q,t).
// grid (96, 16), 256 threads, thread handles 4 consecutive q.
// ---------------------------------------------------------------------------
__global__ __launch_bounds__(256) void tws_kernel(
    const float* __restrict__ probs, const float* __restrict__ boxes,
    const int* __restrict__ labels, const float* __restrict__ tgt,
    float* __restrict__ tws)
{
    const int t = blockIdx.x;          // 0..95
    const int b = blockIdx.y;          // 0..15
    const int tr = b * NTGT + t;
    float tv[DD];
#pragma unroll
    for (int d = 0; d < DD; ++d) tv[d] = tgt[(size_t)tr * DD + d];
    const int cls = labels[tr];

    const int q4 = threadIdx.x * 4;
    const int row0 = b * NQ + q4;
    const float4* bx4 = (const float4*)(boxes + (size_t)row0 * DD);
    float bv[24];
#pragma unroll
    for (int c = 0; c < 6; ++c) {
        float4 f = bx4[c];
        bv[c * 4] = f.x; bv[c * 4 + 1] = f.y; bv[c * 4 + 2] = f.z; bv[c * 4 + 3] = f.w;
    }
    const float4* pr4 = (const float4*)(probs + (size_t)row0 * 4);
    float o[4];
#pragma unroll
    for (int c = 0; c < 4; ++c) {
        float4 p = pr4[c];
        float ps = (cls == 0) ? p.x : (cls == 1) ? p.y : (cls == 2) ? p.z : p.w;
        o[c] = cost_elem6(bv + c * DD, tv, ps);
    }
    *((float4*)(tws + (size_t)tr * NQ + q4)) = make_float4(o[0], o[1], o[2], o[3]);
}

// ---------------------------------------------------------------------------
// Fallback cost kernel (round-1 style): full C, probs computed inline.
// ---------------------------------------------------------------------------
__global__ __launch_bounds__(384) void cost_kernel_fb(
    const float* __restrict__ logits, const float* __restrict__ boxes,
    const int* __restrict__ labels, const float* __restrict__ tgt,
    float* __restrict__ C)
{
    const int row = blockIdx.x;
    const int tid = threadIdx.x;
    const float4 lg = *reinterpret_cast<const float4*>(logits + (size_t)row * NCLS);
    const float mx = fmaxf(fmaxf(lg.x, lg.y), fmaxf(lg.z, lg.w));
    const float e0 = expf(lg.x - mx), e1 = expf(lg.y - mx);
    const float e2 = expf(lg.z - mx), e3 = expf(lg.w - mx);
    const float s = (e0 + e1) + (e2 + e3);
    float prr[4] = {e0 / s, e1 / s, e2 / s, e3 / s};

    float bx[DD];
#pragma unroll
    for (int d = 0; d < DD; ++d) bx[d] = boxes[(size_t)row * DD + d];

    const int colbase = tid * 4;
    const int4 lb = *reinterpret_cast<const int4*>(labels + colbase);
    const int cls[4] = {lb.x, lb.y, lb.z, lb.w};
    float tv[24];
    const float4* tg = reinterpret_cast<const float4*>(tgt + (size_t)colbase * DD);
#pragma unroll
    for (int d = 0; d < 6; ++d) {
        const float4 t4 = tg[d];
        tv[d * 4] = t4.x; tv[d * 4 + 1] = t4.y; tv[d * 4 + 2] = t4.z; tv[d * 4 + 3] = t4.w;
    }
    float o[4];
#pragma unroll
    for (int c = 0; c < 4; ++c) {
        const int cl = cls[c];
        const float ps = (cl & 2) ? ((cl & 1) ? prr[3] : prr[2]) : ((cl & 1) ? prr[1] : prr[0]);
        o[c] = cost_elem6(bx, tv + c * DD, ps);
    }
    *reinterpret_cast<float4*>(C + (size_t)row * NCOLS + colbase) =
        make_float4(o[0], o[1], o[2], o[3]);
}

// ---------------------------------------------------------------------------
// Fused kernel: blocks 0..15 = hungarian (1 wave each), blocks 16.. = C build.
// ---------------------------------------------------------------------------
__global__ __launch_bounds__(256) void fused_kernel(
    const float* __restrict__ tws, const float* __restrict__ probs,
    const float* __restrict__ boxes, const int* __restrict__ labels,
    const float* __restrict__ tgt, float* __restrict__ C,
    float* __restrict__ out_match, int strided)
{
    if (blockIdx.x >= NHB) {
        // ---- C production: one q-row per block ----
        const int row = blockIdx.x - NHB;
        float bx[DD];
#pragma unroll
        for (int d = 0; d < DD; ++d) bx[d] = boxes[(size_t)row * DD + d];
        const float4 pr = ((const float4*)probs)[row];
        const float prr[4] = {pr.x, pr.y, pr.z, pr.w};
        const int tid = threadIdx.x;
        for (int g = tid; g < 384; g += 256) {
            const int colbase = g * 4;
            const int4 lb = ((const int4*)labels)[g];
            const int cls[4] = {lb.x, lb.y, lb.z, lb.w};
            const float4* tg = (const float4*)(tgt + (size_t)colbase * DD);
            float tv[24];
#pragma unroll
            for (int c = 0; c < 6; ++c) {
                float4 f = tg[c];
                tv[c * 4] = f.x; tv[c * 4 + 1] = f.y; tv[c * 4 + 2] = f.z; tv[c * 4 + 3] = f.w;
            }
            float o[4];
#pragma unroll
            for (int c = 0; c < 4; ++c) {
                const int cl = cls[c];
                const float ps = (cl & 2) ? ((cl & 1) ? prr[3] : prr[2])
                                          : ((cl & 1) ? prr[1] : prr[0]);
                o[c] = cost_elem6(bx, tv + c * DD, ps);
            }
            *((float4*)(C + (size_t)row * NCOLS + colbase)) =
                make_float4(o[0], o[1], o[2], o[3]);
        }
        return;
    }

    // ---- Hungarian: one wave per batch ----
    if (threadIdx.x >= 64) return;
    const int b = blockIdx.x;
    const int lane = threadIdx.x;

    __shared__ float u_lds[NTGT + 1];
    __shared__ int   p_lds[NQ];      // index j-1 -> matched row (0 = free)
    __shared__ float dmark[NQ];      // cumulative Delta at marking time

    for (int t = lane; t < NQ; t += 64) p_lds[t] = 0;
    for (int t = lane; t < NTGT + 1; t += 64) u_lds[t] = 0.f;
    __builtin_amdgcn_wave_barrier();

    const int jbase = lane * 16;     // lane owns j-1 in [jbase, jbase+16)
    const float* Tb = tws + (size_t)b * NTGT * NQ;
    const float* Cstr = C + (size_t)b * NQ * NCOLS + b * NTGT;

    float v[16], Msel[16], msk[16];
    int way[16], p_reg[16];
#pragma unroll
    for (int k = 0; k < 16; ++k) v[k] = 0.f;

    for (int i = 1; i <= NTGT; ++i) {
        // mirror p into registers (post-augment state)
        const int4* pl4 = (const int4*)(p_lds + jbase);
#pragma unroll
        for (int c = 0; c < 4; ++c) {
            int4 pp = pl4[c];
            p_reg[c * 4] = pp.x; p_reg[c * 4 + 1] = pp.y;
            p_reg[c * 4 + 2] = pp.z; p_reg[c * 4 + 3] = pp.w;
        }
#pragma unroll
        for (int k = 0; k < 16; ++k) { Msel[k] = LHINF; msk[k] = -LHINF; way[k] = 0; }
        unsigned used = 0u;
        int i0 = i; float Delta = 0.f; int j0cur = 0;
        bool domark = false; int markk = 0;
        float Dfinal = 0.f; int jfreem1 = 0;

        for (;;) {
            // ---- issue cost-row loads for i0 ----
            float av[16];
            if (!strided) {
                const float4* rp = (const float4*)(Tb + (size_t)(i0 - 1) * NQ + jbase);
#pragma unroll
                for (int c = 0; c < 4; ++c) {
                    float4 f = rp[c];
                    av[c * 4] = f.x; av[c * 4 + 1] = f.y;
                    av[c * 4 + 2] = f.z; av[c * 4 + 3] = f.w;
                }
            } else {
                const float* cp = Cstr + (i0 - 1);
#pragma unroll
                for (int k = 0; k < 16; ++k) av[k] = cp[(size_t)(jbase + k) * NCOLS];
            }
            const float u_i0 = u_lds[i0];

            // ---- deferred marking of previous winner (hidden under loads) ----
#pragma unroll
            for (int k = 0; k < 16; ++k) {
                const bool mk = domark && (markk == k);
                Msel[k] = mk ? LHINF : Msel[k];
                msk[k]  = mk ? LHINF : msk[k];
            }
            used |= (domark ? (1u << markk) : 0u);

            const float c0 = Delta - u_i0;
            float lbv = LHINF; int lbk = 0; int lbp = 0;
#pragma unroll
            for (int k = 0; k < 16; ++k) {
                float cand = (av[k] - v[k]) + c0;
                cand = fmaxf(cand, msk[k]);          // used -> +INF
                const bool better = cand < Msel[k];
                way[k]  = better ? j0cur : way[k];
                Msel[k] = better ? cand : Msel[k];
                const bool b2 = Msel[k] < lbv;       // strict: first-index ties
                lbv = b2 ? Msel[k] : lbv;
                lbk = b2 ? k : lbk;
                lbp = b2 ? p_reg[k] : lbp;
            }
            // ---- wave argmin: DPP value-min, ballot for first lane ----
            const float red = wave_fmin63(lbv);
            const float gmin = __int_as_float(
                __builtin_amdgcn_readlane(__float_as_int(red), 63));
            const unsigned long long bal = __ballot(lbv == gmin);
            const int W = __builtin_amdgcn_readfirstlane((int)__builtin_ctzll(bal));
            const int lbjm1 = jbase + lbk;
            const int j1m1 = __builtin_amdgcn_readlane(lbjm1, W);
            const int i0n  = __builtin_amdgcn_readlane(lbp, W);
            const bool iswin = (lane == W);
            if (iswin) dmark[lbjm1] = lbv;           // Delta at marking
            domark = iswin; markk = lbk;
            if (i0n == 0) { Dfinal = gmin; jfreem1 = j1m1; break; }
            Delta = gmin; i0 = i0n; j0cur = j1m1 + 1;
        }

        // ---- row end: reconstruct dual updates ----
        __builtin_amdgcn_wave_barrier();
        float dmv[16];
        const float4* dm4 = (const float4*)(dmark + jbase);
#pragma unroll
        for (int c = 0; c < 4; ++c) {
            float4 f = dm4[c];
            dmv[c * 4] = f.x; dmv[c * 4 + 1] = f.y;
            dmv[c * 4 + 2] = f.z; dmv[c * 4 + 3] = f.w;
        }
#pragma unroll
        for (int k = 0; k < 16; ++k) {
            if ((used >> k) & 1u) {
                const float d = Dfinal - dmv[k];
                v[k] -= d;
                u_lds[p_reg[k]] += d;   // distinct addresses (p injective)
            }
        }
        if (lane == 0) u_lds[i] += Dfinal;   // virtual col 0 (marked at Delta=0)
        __builtin_amdgcn_wave_barrier();

        // ---- augmenting path ----
        int j0m1 = jfreem1;
        for (;;) {
            const int kk = j0m1 & 15;
            const int owner = __builtin_amdgcn_readfirstlane(j0m1 >> 4);
            // 16-way register select of way[kk] (kk wave-uniform)
            int s0 = (kk & 1) ? way[1]  : way[0];
            int s1 = (kk & 1) ? way[3]  : way[2];
            int s2 = (kk & 1) ? way[5]  : way[4];
            int s3 = (kk & 1) ? way[7]  : way[6];
            int s4 = (kk & 1) ? way[9]  : way[8];
            int s5 = (kk & 1) ? way[11] : way[10];
            int s6 = (kk & 1) ? way[13] : way[12];
            int s7 = (kk & 1) ? way[15] : way[14];
            int t0 = (kk & 2) ? s1 : s0;
            int t1 = (kk & 2) ? s3 : s2;
            int t2 = (kk & 2) ? s5 : s4;
            int t3 = (kk & 2) ? s7 : s6;
            int q0 = (kk & 4) ? t1 : t0;
            int q1 = (kk & 4) ? t3 : t2;
            int wsel = (kk & 8) ? q1 : q0;
            const int jn = __builtin_amdgcn_readlane(wsel, owner);  // 1-based col
            const int pv = (jn == 0) ? i : p_lds[jn - 1];
            if (lane == 0) p_lds[j0m1] = pv;
            __builtin_amdgcn_wave_barrier();
            if (jn == 0) break;
            j0m1 = jn - 1;
        }
    }

    // invert: matched query (col j-1) for each target row
    for (int t = lane; t < NQ; t += 64) {
        const int r = p_lds[t];
        if (r > 0) out_match[b * NTGT + r - 1] = (float)t;
    }
}

extern "C" void kernel_launch(void* const* d_in, const int* in_sizes, int n_in,
                              void* d_out, int out_size, void* d_ws, size_t ws_size,
                              hipStream_t stream) {
    const float* logits = (const float*)d_in[0];   // (16,1024,4)
    const float* boxes  = (const float*)d_in[1];   // (16,1024,6)
    const int*   labels = (const int*)d_in[2];     // (16,96)
    const float* tgt    = (const float*)d_in[3];   // (16,96,6)

    float* C = (float*)d_out;
    float* out_match = C + (size_t)NROWS * NCOLS;

    const size_t probs_elems = (size_t)NROWS * 4;
    const size_t need = (probs_elems + (size_t)NCOLS * NQ) * sizeof(float);
    if (d_ws != nullptr && ws_size >= need) {
        float* probs = (float*)d_ws;
        float* tws = probs + probs_elems;
        probs_kernel<<<NROWS / 256, 256, 0, stream>>>(logits, probs);
        tws_kernel<<<dim3(NTGT, BSZ), 256, 0, stream>>>(probs, boxes, labels, tgt, tws);
        fused_kernel<<<NHB + NROWS, 256, 0, stream>>>(
            tws, probs, boxes, labels, tgt, C, out_match, 0);
    } else {
        // fallback: serial cost kernel then strided hungarian
        cost_kernel_fb<<<NROWS, 384, 0, stream>>>(logits, boxes, labels, tgt, C);
        fused_kernel<<<NHB, 64, 0, stream>>>(
            nullptr, nullptr, boxes, labels, tgt, C, out_match, 1);
    }
}

// Round 5
// 174.382 us; speedup vs baseline: 5.1699x; 1.6505x over previous
//
#include <hip/hip_runtime.h>

// HungarianMatcher on MI355X (gfx950).
// Output 0: C (16, 1024, 1536) fp32 cost matrix.
// Output 1: matched_query (16, 96) written as fp32 values.
//
// R5: warm start fixed. R3/R4 used v[q]=colmin warm start, which violates
// rectangular-LAP complementary slackness (unmatched columns must end with
// v=0) -> deterministic wrong assignment (identical absmax both rounds).
// Now: u[t] = row min (row reduction), v = 0, greedy tight-edge assignment
// (first-t wins), Dijkstra (R2-verified shifted-potential machinery,
// unchanged) only for collided rows. Provably exact.
// Also fused row-min/argmin into the tws producer and inlined softmax
// everywhere: 2 kernels total.

#define BSZ   16
#define NQ    1024
#define NTGT  96
#define NCLS  4
#define DD    6
#define NCOLS (BSZ * NTGT)   // 1536
#define NROWS (BSZ * NQ)     // 16384
#define LHINF 1e9f
#define NHB   16

// ---------------------------------------------------------------------------
__device__ __forceinline__ float wave_fmin63(float x) {
    const int INF_I = __float_as_int(LHINF);
    int m;
    m = __builtin_amdgcn_update_dpp(INF_I, __float_as_int(x), 0x111, 0xf, 0xf, false);
    x = fminf(x, __int_as_float(m));
    m = __builtin_amdgcn_update_dpp(INF_I, __float_as_int(x), 0x112, 0xf, 0xf, false);
    x = fminf(x, __int_as_float(m));
    m = __builtin_amdgcn_update_dpp(INF_I, __float_as_int(x), 0x114, 0xf, 0xf, false);
    x = fminf(x, __int_as_float(m));
    m = __builtin_amdgcn_update_dpp(INF_I, __float_as_int(x), 0x118, 0xf, 0xf, false);
    x = fminf(x, __int_as_float(m));
    m = __builtin_amdgcn_update_dpp(INF_I, __float_as_int(x), 0x142, 0xf, 0xf, false);
    x = fminf(x, __int_as_float(m));
    m = __builtin_amdgcn_update_dpp(INF_I, __float_as_int(x), 0x143, 0xf, 0xf, false);
    x = fminf(x, __int_as_float(m));
    return x;
}

__device__ __forceinline__ float cost_elem6(const float* bx, const float* tv, float psel) {
    float cd = fabsf(bx[0] - tv[0]);
    cd += fabsf(bx[1] - tv[1]);
    cd += fabsf(bx[2] - tv[2]);
    cd += fabsf(bx[3] - tv[3]);
    cd += fabsf(bx[4] - tv[4]);
    cd += fabsf(bx[5] - tv[5]);
    return cd - psel;
}

// Shared softmax so tws and C agree exactly.
__device__ __forceinline__ float4 softmax4(float4 lg) {
    const float mx = fmaxf(fmaxf(lg.x, lg.y), fmaxf(lg.z, lg.w));
    const float e0 = expf(lg.x - mx), e1 = expf(lg.y - mx);
    const float e2 = expf(lg.z - mx), e3 = expf(lg.w - mx);
    const float s = (e0 + e1) + (e2 + e3);
    return make_float4(e0 / s, e1 / s, e2 / s, e3 / s);
}

// ---------------------------------------------------------------------------
// twsarg: tws[(b*96+t)*1024 + q] = cost(b,q,t); rowminv/rowarg = min/argmin
// over q (first-index tie-break). grid (96,16) x 256 threads, 4 q per thread.
// ---------------------------------------------------------------------------
__global__ __launch_bounds__(256) void twsarg_kernel(
    const float* __restrict__ logits, const float* __restrict__ boxes,
    const int* __restrict__ labels, const float* __restrict__ tgt,
    float* __restrict__ tws, float* __restrict__ rowminv, int* __restrict__ rowarg)
{
    const int t = blockIdx.x;
    const int b = blockIdx.y;
    const int tr = b * NTGT + t;
    float tv[DD];
#pragma unroll
    for (int d = 0; d < DD; ++d) tv[d] = tgt[(size_t)tr * DD + d];
    const int cls = labels[tr];

    const int q4 = threadIdx.x * 4;
    const int row0 = b * NQ + q4;
    const float4* bx4 = (const float4*)(boxes + (size_t)row0 * DD);
    float bv[24];
#pragma unroll
    for (int c = 0; c < 6; ++c) {
        float4 f = bx4[c];
        bv[c * 4] = f.x; bv[c * 4 + 1] = f.y; bv[c * 4 + 2] = f.z; bv[c * 4 + 3] = f.w;
    }
    float o[4];
#pragma unroll
    for (int c = 0; c < 4; ++c) {
        const float4 p = softmax4(((const float4*)logits)[row0 + c]);
        const float ps = (cls == 0) ? p.x : (cls == 1) ? p.y : (cls == 2) ? p.z : p.w;
        o[c] = cost_elem6(bv + c * DD, tv, ps);
    }
    *((float4*)(tws + (size_t)tr * NQ + q4)) = make_float4(o[0], o[1], o[2], o[3]);

    // block min/argmin over 1024 q, first-index ties
    float bvv = o[0]; int bj = q4;
    if (o[1] < bvv) { bvv = o[1]; bj = q4 + 1; }
    if (o[2] < bvv) { bvv = o[2]; bj = q4 + 2; }
    if (o[3] < bvv) { bvv = o[3]; bj = q4 + 3; }
#pragma unroll
    for (int off = 32; off > 0; off >>= 1) {
        const float ov = __shfl_down(bvv, off, 64);
        const int oj = __shfl_down(bj, off, 64);
        if (ov < bvv || (ov == bvv && oj < bj)) { bvv = ov; bj = oj; }
    }
    __shared__ float sv[4];
    __shared__ int sj[4];
    const int w = threadIdx.x >> 6;
    if ((threadIdx.x & 63) == 0) { sv[w] = bvv; sj[w] = bj; }
    __syncthreads();
    if (threadIdx.x == 0) {
        for (int i = 1; i < 4; ++i)
            if (sv[i] < bvv || (sv[i] == bvv && sj[i] < bj)) { bvv = sv[i]; bj = sj[i]; }
        rowminv[tr] = bvv; rowarg[tr] = bj;
    }
}

// Fallback cost kernel (no ws): full C, probs inline.
__global__ __launch_bounds__(384) void cost_kernel_fb(
    const float* __restrict__ logits, const float* __restrict__ boxes,
    const int* __restrict__ labels, const float* __restrict__ tgt,
    float* __restrict__ C)
{
    const int row = blockIdx.x;
    const int tid = threadIdx.x;
    const float4 pr = softmax4(*reinterpret_cast<const float4*>(logits + (size_t)row * NCLS));
    const float prr[4] = {pr.x, pr.y, pr.z, pr.w};
    float bx[DD];
#pragma unroll
    for (int d = 0; d < DD; ++d) bx[d] = boxes[(size_t)row * DD + d];
    const int colbase = tid * 4;
    const int4 lb = *reinterpret_cast<const int4*>(labels + colbase);
    const int cls[4] = {lb.x, lb.y, lb.z, lb.w};
    float tv[24];
    const float4* tg = reinterpret_cast<const float4*>(tgt + (size_t)colbase * DD);
#pragma unroll
    for (int d = 0; d < 6; ++d) {
        const float4 t4 = tg[d];
        tv[d * 4] = t4.x; tv[d * 4 + 1] = t4.y; tv[d * 4 + 2] = t4.z; tv[d * 4 + 3] = t4.w;
    }
    float o[4];
#pragma unroll
    for (int c = 0; c < 4; ++c) {
        const int cl = cls[c];
        const float ps = (cl == 0) ? prr[0] : (cl == 1) ? prr[1] : (cl == 2) ? prr[2] : prr[3];
        o[c] = cost_elem6(bx, tv + c * DD, ps);
    }
    *reinterpret_cast<float4*>(C + (size_t)row * NCOLS + colbase) =
        make_float4(o[0], o[1], o[2], o[3]);
}

// ---------------------------------------------------------------------------
// Fused: blocks 0..15 hungarian (1 wave), blocks 16.. build C (softmax inline).
// ---------------------------------------------------------------------------
__global__ __launch_bounds__(256) void fused_kernel(
    const float* __restrict__ tws, const float* __restrict__ logits,
    const float* __restrict__ boxes, const int* __restrict__ labels,
    const float* __restrict__ tgt,
    const float* __restrict__ rowminv, const int* __restrict__ rowarg,
    float* __restrict__ C, float* __restrict__ out_match, int warm)
{
    if (blockIdx.x >= NHB) {
        const int row = blockIdx.x - NHB;
        float bx[DD];
#pragma unroll
        for (int d = 0; d < DD; ++d) bx[d] = boxes[(size_t)row * DD + d];
        const float4 pr = softmax4(((const float4*)logits)[row]);
        const float prr[4] = {pr.x, pr.y, pr.z, pr.w};
        const int tid = threadIdx.x;
        for (int g = tid; g < 384; g += 256) {
            const int colbase = g * 4;
            const int4 lb = ((const int4*)labels)[g];
            const int cls[4] = {lb.x, lb.y, lb.z, lb.w};
            const float4* tg = (const float4*)(tgt + (size_t)colbase * DD);
            float tv[24];
#pragma unroll
            for (int c = 0; c < 6; ++c) {
                float4 f = tg[c];
                tv[c * 4] = f.x; tv[c * 4 + 1] = f.y; tv[c * 4 + 2] = f.z; tv[c * 4 + 3] = f.w;
            }
            float o[4];
#pragma unroll
            for (int c = 0; c < 4; ++c) {
                const int cl = cls[c];
                const float ps = (cl == 0) ? prr[0] : (cl == 1) ? prr[1]
                               : (cl == 2) ? prr[2] : prr[3];
                o[c] = cost_elem6(bx, tv + c * DD, ps);
            }
            *((float4*)(C + (size_t)row * NCOLS + colbase)) =
                make_float4(o[0], o[1], o[2], o[3]);
        }
        return;
    }

    // ---- Hungarian: one wave per batch ----
    if (threadIdx.x >= 64) return;
    const int b = blockIdx.x;
    const int lane = threadIdx.x;

    __shared__ float u_lds[NTGT + 1];
    __shared__ int   p_lds[NQ];
    __shared__ float dmark[NQ];
    __shared__ int   ja_s[NTGT];
    __shared__ float um_s[NTGT];
    __shared__ int   pendf[NTGT];

    for (int t = lane; t < NQ; t += 64) p_lds[t] = 0;
    for (int t = lane; t < NTGT + 1; t += 64) u_lds[t] = 0.f;
    __builtin_amdgcn_wave_barrier();

    const int jbase = lane * 16;
    const float* Tb = tws + (size_t)b * NTGT * NQ;
    const float* Cstr = C + (size_t)b * NQ * NCOLS + b * NTGT;

    float v[16], Msel[16], msk[16];
    int way[16], p_reg[16];
#pragma unroll
    for (int k = 0; k < 16; ++k) v[k] = 0.f;   // v = 0: rectangular CS holds

    if (warm) {
        // stage greedy inputs into LDS
        for (int t = lane; t < NTGT; t += 64) {
            ja_s[t] = rowarg[b * NTGT + t];
            um_s[t] = rowminv[b * NTGT + t];
        }
        __builtin_amdgcn_wave_barrier();
        // lane-0 serial greedy: first-t wins; u[t] = row min for winners.
        // (u[t]=rowmin, v=0, matched edges tight -> valid JV state.)
        if (lane == 0) {
            for (int t = 0; t < NTGT; ++t) {
                const int jt = ja_s[t];
                if (p_lds[jt] == 0) {
                    p_lds[jt] = t + 1;
                    u_lds[t + 1] = um_s[t];
                    pendf[t] = 0;
                } else {
                    pendf[t] = 1;
                }
            }
        }
        __builtin_amdgcn_wave_barrier();
    } else {
        for (int t = lane; t < NTGT; t += 64) pendf[t] = 1;
        __builtin_amdgcn_wave_barrier();
    }

    // ---- Dijkstra only for pending rows (R2-verified machinery) ----
    for (int tt = 0; tt < NTGT; ++tt) {
        const int pending = __builtin_amdgcn_readfirstlane(pendf[tt]);
        if (!pending) continue;
        const int i = tt + 1;

        const int4* pl4 = (const int4*)(p_lds + jbase);
#pragma unroll
        for (int c = 0; c < 4; ++c) {
            int4 pp = pl4[c];
            p_reg[c * 4] = pp.x; p_reg[c * 4 + 1] = pp.y;
            p_reg[c * 4 + 2] = pp.z; p_reg[c * 4 + 3] = pp.w;
        }
#pragma unroll
        for (int k = 0; k < 16; ++k) { Msel[k] = LHINF; msk[k] = -LHINF; way[k] = 0; }
        unsigned used = 0u;
        int i0 = i; float Delta = 0.f; int j0cur = 0;
        bool domark = false; int markk = 0;
        float Dfinal = 0.f; int jfreem1 = 0;

        for (;;) {
            float av[16];
            if (warm) {
                const float4* rp = (const float4*)(Tb + (size_t)(i0 - 1) * NQ + jbase);
#pragma unroll
                for (int c = 0; c < 4; ++c) {
                    float4 f = rp[c];
                    av[c * 4] = f.x; av[c * 4 + 1] = f.y;
                    av[c * 4 + 2] = f.z; av[c * 4 + 3] = f.w;
                }
            } else {
                const float* cp = Cstr + (i0 - 1);
#pragma unroll
                for (int k = 0; k < 16; ++k) av[k] = cp[(size_t)(jbase + k) * NCOLS];
            }
            const float u_i0 = u_lds[i0];

#pragma unroll
            for (int k = 0; k < 16; ++k) {
                const bool mk = domark && (markk == k);
                Msel[k] = mk ? LHINF : Msel[k];
                msk[k]  = mk ? LHINF : msk[k];
            }
            used |= (domark ? (1u << markk) : 0u);

            const float c0 = Delta - u_i0;
            float lbv = LHINF; int lbk = 0; int lbp = 0;
#pragma unroll
            for (int k = 0; k < 16; ++k) {
                float cand = (av[k] - v[k]) + c0;
                cand = fmaxf(cand, msk[k]);
                const bool better = cand < Msel[k];
                way[k]  = better ? j0cur : way[k];
                Msel[k] = better ? cand : Msel[k];
                const bool b2 = Msel[k] < lbv;
                lbv = b2 ? Msel[k] : lbv;
                lbk = b2 ? k : lbk;
                lbp = b2 ? p_reg[k] : lbp;
            }
            const float red = wave_fmin63(lbv);
            const float gmin = __int_as_float(
                __builtin_amdgcn_readlane(__float_as_int(red), 63));
            const unsigned long long bal = __ballot(lbv == gmin);
            const int W = __builtin_amdgcn_readfirstlane((int)__builtin_ctzll(bal));
            const int lbjm1 = jbase + lbk;
            const int j1m1 = __builtin_amdgcn_readlane(lbjm1, W);
            const int i0n  = __builtin_amdgcn_readlane(lbp, W);
            const bool iswin = (lane == W);
            if (iswin) dmark[lbjm1] = lbv;
            domark = iswin; markk = lbk;
            if (i0n == 0) { Dfinal = gmin; jfreem1 = j1m1; break; }
            Delta = gmin; i0 = i0n; j0cur = j1m1 + 1;
        }

        __builtin_amdgcn_wave_barrier();
        float dmv[16];
        const float4* dm4 = (const float4*)(dmark + jbase);
#pragma unroll
        for (int c = 0; c < 4; ++c) {
            float4 f = dm4[c];
            dmv[c * 4] = f.x; dmv[c * 4 + 1] = f.y;
            dmv[c * 4 + 2] = f.z; dmv[c * 4 + 3] = f.w;
        }
#pragma unroll
        for (int k = 0; k < 16; ++k) {
            if ((used >> k) & 1u) {
                const float d = Dfinal - dmv[k];
                v[k] -= d;
                u_lds[p_reg[k]] += d;
            }
        }
        if (lane == 0) u_lds[i] += Dfinal;
        __builtin_amdgcn_wave_barrier();

        int j0m1 = jfreem1;
        for (;;) {
            const int kk = j0m1 & 15;
            const int owner = __builtin_amdgcn_readfirstlane(j0m1 >> 4);
            int s0 = (kk & 1) ? way[1]  : way[0];
            int s1 = (kk & 1) ? way[3]  : way[2];
            int s2 = (kk & 1) ? way[5]  : way[4];
            int s3 = (kk & 1) ? way[7]  : way[6];
            int s4 = (kk & 1) ? way[9]  : way[8];
            int s5 = (kk & 1) ? way[11] : way[10];
            int s6 = (kk & 1) ? way[13] : way[12];
            int s7 = (kk & 1) ? way[15] : way[14];
            int t0 = (kk & 2) ? s1 : s0;
            int t1 = (kk & 2) ? s3 : s2;
            int t2 = (kk & 2) ? s5 : s4;
            int t3 = (kk & 2) ? s7 : s6;
            int q0 = (kk & 4) ? t1 : t0;
            int q1 = (kk & 4) ? t3 : t2;
            int wsel = (kk & 8) ? q1 : q0;
            const int jn = __builtin_amdgcn_readlane(wsel, owner);
            const int pv = (jn == 0) ? i : p_lds[jn - 1];
            if (lane == 0) p_lds[j0m1] = pv;
            __builtin_amdgcn_wave_barrier();
            if (jn == 0) break;
            j0m1 = jn - 1;
        }
    }

    for (int t = lane; t < NQ; t += 64) {
        const int r = p_lds[t];
        if (r > 0) out_match[b * NTGT + r - 1] = (float)t;
    }
}

extern "C" void kernel_launch(void* const* d_in, const int* in_sizes, int n_in,
                              void* d_out, int out_size, void* d_ws, size_t ws_size,
                              hipStream_t stream) {
    const float* logits = (const float*)d_in[0];
    const float* boxes  = (const float*)d_in[1];
    const int*   labels = (const int*)d_in[2];
    const float* tgt    = (const float*)d_in[3];

    float* C = (float*)d_out;
    float* out_match = C + (size_t)NROWS * NCOLS;

    const size_t tws_e = (size_t)NCOLS * NQ;      // 1572864
    const size_t rmv_e = (size_t)NCOLS;           // 1536
    const size_t need = (tws_e + rmv_e * 2) * sizeof(float);

    if (d_ws != nullptr && ws_size >= need) {
        float* tws     = (float*)d_ws;
        float* rowminv = tws + tws_e;
        int*   rowarg  = (int*)(rowminv + rmv_e);
        twsarg_kernel<<<dim3(NTGT, BSZ), 256, 0, stream>>>(
            logits, boxes, labels, tgt, tws, rowminv, rowarg);
        fused_kernel<<<NHB + NROWS, 256, 0, stream>>>(
            tws, logits, boxes, labels, tgt, rowminv, rowarg, C, out_match, 1);
    } else {
        cost_kernel_fb<<<NROWS, 384, 0, stream>>>(logits, boxes, labels, tgt, C);
        fused_kernel<<<NHB, 64, 0, stream>>>(
            nullptr, logits, boxes, labels, tgt, nullptr, nullptr, C, out_match, 0);
    }
}